// Round 6
// baseline (616.723 us; speedup 1.0000x reference)
//
#include <hip/hip_runtime.h>

#define N_NODES 50000
#define N_EDGES 600000
#define IN_CH 64
#define HID 128
#define N_GRAPHS 64

typedef __attribute__((ext_vector_type(8))) short bf16x8;
typedef __attribute__((ext_vector_type(4))) float f32x4;

// ---- bf16 helpers (manual, RNE) ----
__device__ __forceinline__ float bf2f(unsigned short u) {
    union { unsigned int i; float f; } v; v.i = ((unsigned int)u) << 16; return v.f;
}
__device__ __forceinline__ unsigned short f2bf(float f) {
    union { float f; unsigned int i; } v; v.f = f;
    unsigned int u = v.i;
    return (unsigned short)((u + 0x7FFFu + ((u >> 16) & 1u)) >> 16);
}

// ===========================================================================
// CSR build: counting-sort edges by dst; edata[pos] = {src, a0, a1, a2}.
// ===========================================================================
__global__ void hist_kernel(const int* __restrict__ ei, int* __restrict__ deg) {
    int e = blockIdx.x * blockDim.x + threadIdx.x;
    if (e < N_EDGES) atomicAdd(&deg[ei[N_EDGES + e]], 1);
}

__global__ void scan_kernel(const int* __restrict__ deg,
                            int* __restrict__ rowptr,
                            int* __restrict__ cursor) {
    __shared__ int partial[1024];
    const int t = threadIdx.x;
    const int CHUNK = (N_NODES + 1023) / 1024;  // 49
    int begin = t * CHUNK;
    int end = begin + CHUNK; if (end > N_NODES) end = N_NODES;
    int sum = 0;
    for (int i = begin; i < end; i++) sum += deg[i];
    int val = sum;
    partial[t] = val;
    __syncthreads();
    for (int off = 1; off < 1024; off <<= 1) {
        int n = (t >= off) ? partial[t - off] : 0;
        __syncthreads();
        val += n;
        partial[t] = val;
        __syncthreads();
    }
    int run = val - sum;
    for (int i = begin; i < end; i++) { rowptr[i] = run; cursor[i] = run; run += deg[i]; }
    if (t == 1023) rowptr[N_NODES] = run;
}

__global__ void scatter_kernel(const int* __restrict__ ei,
                               const float* __restrict__ ea,
                               int* __restrict__ cursor,
                               int4* __restrict__ edata) {
    int e = blockIdx.x * blockDim.x + threadIdx.x;
    if (e < N_EDGES) {
        int dst = ei[N_EDGES + e];
        int pos = atomicAdd(&cursor[dst], 1);
        edata[pos] = make_int4(ei[e],
                               __float_as_int(ea[3 * e]),
                               __float_as_int(ea[3 * e + 1]),
                               __float_as_int(ea[3 * e + 2]));
    }
}

// f32 -> bf16 for input features
__global__ void cvt_kernel(const float* __restrict__ in, unsigned short* __restrict__ out,
                           int n) {
    int i = blockIdx.x * blockDim.x + threadIdx.x;
    if (i < n) out[i] = f2bf(in[i]);
}

// transpose + bf16: wT[n*Kdim + k] = w[k*Ndim + n]   (w is [Kdim, Ndim])
__global__ void tw_kernel(const float* __restrict__ w, unsigned short* __restrict__ wT,
                          int Kdim, int Ndim) {
    int i = blockIdx.x * blockDim.x + threadIdx.x;
    if (i < Kdim * Ndim) {
        int k = i / Ndim, n = i % Ndim;
        wT[n * Kdim + k] = f2bf(w[k * Ndim + n]);
    }
}

// ===========================================================================
// Fused GINE layer, 256 threads / 16 nodes per block.
// Phase 1 (gather): wave w aggregates nodes 4w..4w+3 into LDS sIn (bf16).
//   K=128: 2 ch/lane via uint row loads (1 wave-load = full 256B row).
//   K=64 : 1 ch/lane ushort row loads.
// Phase 2 (MLP): MFMA 16x16x32_bf16. Wave w owns out channels [32w,32w+32):
//   layer A: [16 x K] @ waT -> relu -> sHid (bf16, LDS)
//   layer B: [16 x 128] @ wbT -> relu -> out
// LDS rows padded +8 shorts to break the stride-256B b128 read conflict.
// ===========================================================================
template <int K, bool POOL>
__global__ __launch_bounds__(256, 4)
void fused_layer(const unsigned short* __restrict__ xin,  // bf16 [N,K]
                 const int4* __restrict__ edata,
                 const int* __restrict__ rowptr,
                 const float* __restrict__ elw,   // [3, K] f32
                 const float* __restrict__ elb,   // [K] f32
                 const unsigned short* __restrict__ waT,  // bf16 [HID, K]
                 const float* __restrict__ ba,
                 const unsigned short* __restrict__ wbT,  // bf16 [HID, HID]
                 const float* __restrict__ bb,
                 void* __restrict__ outv,         // bf16 h [N,HID] or f32 psum
                 const int* __restrict__ batch) {
    constexpr int SSTR = K + 8;     // sIn row stride (shorts)
    constexpr int HSTR = HID + 8;   // sHid row stride (shorts)
    __shared__ __align__(16) unsigned short sIn[16 * SSTR];
    __shared__ __align__(16) unsigned short sHid[16 * HSTR];
    const int t = threadIdx.x;
    const int w = t >> 6, l = t & 63;
    const int node0 = blockIdx.x * 16;

    // ---------------- phase 1: gather ----------------
    if (K == 128) {
        const unsigned* xin32 = (const unsigned*)xin;   // row = 64 uints
        const int c0 = 2 * l;
        const float w00 = elw[c0],         w01 = elw[c0 + 1];
        const float w10 = elw[K + c0],     w11 = elw[K + c0 + 1];
        const float w20 = elw[2 * K + c0], w21 = elw[2 * K + c0 + 1];
        const float eb0 = elb[c0],         eb1 = elb[c0 + 1];

        for (int ni = 0; ni < 4; ni++) {
            const int ml = w * 4 + ni;
            const int node = node0 + ml;
            unsigned sv = xin32[(size_t)node * 64 + l];
            float acc0 = bf2f((unsigned short)(sv & 0xFFFF));
            float acc1 = bf2f((unsigned short)(sv >> 16));
            auto term2 = [&](int4 e, unsigned r) {
                float A0 = __int_as_float(e.y), A1 = __int_as_float(e.z), A2 = __int_as_float(e.w);
                float ev0 = A0 * w00 + A1 * w10 + A2 * w20 + eb0;
                float ev1 = A0 * w01 + A1 * w11 + A2 * w21 + eb1;
                float m0 = bf2f((unsigned short)(r & 0xFFFF)) + ev0;
                float m1 = bf2f((unsigned short)(r >> 16)) + ev1;
                acc0 += m0 > 0.f ? m0 : 0.f;
                acc1 += m1 > 0.f ? m1 : 0.f;
            };
            int jb = rowptr[node], je = rowptr[node + 1];
            int j = jb;
            for (; j + 8 <= je; j += 8) {
                int4 e0 = edata[j],     e1 = edata[j + 1], e2 = edata[j + 2], e3 = edata[j + 3];
                int4 e4 = edata[j + 4], e5 = edata[j + 5], e6 = edata[j + 6], e7 = edata[j + 7];
                unsigned r0 = xin32[(size_t)e0.x * 64 + l];
                unsigned r1 = xin32[(size_t)e1.x * 64 + l];
                unsigned r2 = xin32[(size_t)e2.x * 64 + l];
                unsigned r3 = xin32[(size_t)e3.x * 64 + l];
                unsigned r4 = xin32[(size_t)e4.x * 64 + l];
                unsigned r5 = xin32[(size_t)e5.x * 64 + l];
                unsigned r6 = xin32[(size_t)e6.x * 64 + l];
                unsigned r7 = xin32[(size_t)e7.x * 64 + l];
                term2(e0, r0); term2(e1, r1); term2(e2, r2); term2(e3, r3);
                term2(e4, r4); term2(e5, r5); term2(e6, r6); term2(e7, r7);
            }
            for (; j + 4 <= je; j += 4) {
                int4 e0 = edata[j], e1 = edata[j + 1], e2 = edata[j + 2], e3 = edata[j + 3];
                unsigned r0 = xin32[(size_t)e0.x * 64 + l];
                unsigned r1 = xin32[(size_t)e1.x * 64 + l];
                unsigned r2 = xin32[(size_t)e2.x * 64 + l];
                unsigned r3 = xin32[(size_t)e3.x * 64 + l];
                term2(e0, r0); term2(e1, r1); term2(e2, r2); term2(e3, r3);
            }
            for (; j < je; j++) {
                int4 e0 = edata[j];
                term2(e0, xin32[(size_t)e0.x * 64 + l]);
            }
            ((unsigned*)sIn)[ml * (SSTR / 2) + l] =
                (unsigned)f2bf(acc0) | ((unsigned)f2bf(acc1) << 16);
        }
    } else {  // K == 64: one channel per lane
        const float w0 = elw[l], w1 = elw[K + l], w2 = elw[2 * K + l], eb = elb[l];
        for (int ni = 0; ni < 4; ni++) {
            const int ml = w * 4 + ni;
            const int node = node0 + ml;
            float acc = bf2f(xin[(size_t)node * K + l]);
            auto term1 = [&](int4 e, unsigned short r) {
                float ev = __int_as_float(e.y) * w0 + __int_as_float(e.z) * w1 +
                           __int_as_float(e.w) * w2 + eb;
                float m = bf2f(r) + ev;
                acc += m > 0.f ? m : 0.f;
            };
            int jb = rowptr[node], je = rowptr[node + 1];
            int j = jb;
            for (; j + 8 <= je; j += 8) {
                int4 e0 = edata[j],     e1 = edata[j + 1], e2 = edata[j + 2], e3 = edata[j + 3];
                int4 e4 = edata[j + 4], e5 = edata[j + 5], e6 = edata[j + 6], e7 = edata[j + 7];
                unsigned short r0 = xin[(size_t)e0.x * K + l];
                unsigned short r1 = xin[(size_t)e1.x * K + l];
                unsigned short r2 = xin[(size_t)e2.x * K + l];
                unsigned short r3 = xin[(size_t)e3.x * K + l];
                unsigned short r4 = xin[(size_t)e4.x * K + l];
                unsigned short r5 = xin[(size_t)e5.x * K + l];
                unsigned short r6 = xin[(size_t)e6.x * K + l];
                unsigned short r7 = xin[(size_t)e7.x * K + l];
                term1(e0, r0); term1(e1, r1); term1(e2, r2); term1(e3, r3);
                term1(e4, r4); term1(e5, r5); term1(e6, r6); term1(e7, r7);
            }
            for (; j + 4 <= je; j += 4) {
                int4 e0 = edata[j], e1 = edata[j + 1], e2 = edata[j + 2], e3 = edata[j + 3];
                unsigned short r0 = xin[(size_t)e0.x * K + l];
                unsigned short r1 = xin[(size_t)e1.x * K + l];
                unsigned short r2 = xin[(size_t)e2.x * K + l];
                unsigned short r3 = xin[(size_t)e3.x * K + l];
                term1(e0, r0); term1(e1, r1); term1(e2, r2); term1(e3, r3);
            }
            for (; j < je; j++) {
                int4 e0 = edata[j];
                term1(e0, xin[(size_t)e0.x * K + l]);
            }
            sIn[ml * SSTR + l] = f2bf(acc);
        }
    }
    __syncthreads();

    // ---------------- phase 2: MFMA MLP ----------------
    // lane -> (i16 = col/row-16 index, q = quad); wave w -> out ch [32w, 32w+32)
    const int i16 = l & 15, q = l >> 4;
    const int n0 = w * 32, n1 = n0 + 16;

    // layer A: [16 x K] @ waT^T -> [16 x 128], this wave's 2 16-col tiles
    f32x4 cA0, cA1;
    {
        float bv0 = ba[n0 + i16], bv1 = ba[n1 + i16];
        cA0 = (f32x4){bv0, bv0, bv0, bv0};
        cA1 = (f32x4){bv1, bv1, bv1, bv1};
    }
    {
        const unsigned short* aBase = &sIn[i16 * SSTR + q * 8];
        const unsigned short* b0Base = &waT[(size_t)(n0 + i16) * K + q * 8];
        const unsigned short* b1Base = &waT[(size_t)(n1 + i16) * K + q * 8];
        #pragma unroll
        for (int k0 = 0; k0 < K; k0 += 32) {
            bf16x8 a  = *(const bf16x8*)(aBase + k0);
            bf16x8 b0 = *(const bf16x8*)(b0Base + k0);
            bf16x8 b1 = *(const bf16x8*)(b1Base + k0);
            cA0 = __builtin_amdgcn_mfma_f32_16x16x32_bf16(a, b0, cA0, 0, 0, 0);
            cA1 = __builtin_amdgcn_mfma_f32_16x16x32_bf16(a, b1, cA1, 0, 0, 0);
        }
    }
    // relu -> sHid (bf16). D layout: col = i16, row = q*4+r.
    #pragma unroll
    for (int r = 0; r < 4; r++) {
        int row = q * 4 + r;
        float v0 = cA0[r] > 0.f ? cA0[r] : 0.f;
        float v1 = cA1[r] > 0.f ? cA1[r] : 0.f;
        sHid[row * HSTR + n0 + i16] = f2bf(v0);
        sHid[row * HSTR + n1 + i16] = f2bf(v1);
    }
    __syncthreads();

    // layer B: [16 x 128] @ wbT^T
    f32x4 cB0, cB1;
    {
        float bv0 = bb[n0 + i16], bv1 = bb[n1 + i16];
        cB0 = (f32x4){bv0, bv0, bv0, bv0};
        cB1 = (f32x4){bv1, bv1, bv1, bv1};
    }
    {
        const unsigned short* aBase = &sHid[i16 * HSTR + q * 8];
        const unsigned short* b0Base = &wbT[(size_t)(n0 + i16) * HID + q * 8];
        const unsigned short* b1Base = &wbT[(size_t)(n1 + i16) * HID + q * 8];
        #pragma unroll
        for (int k0 = 0; k0 < HID; k0 += 32) {
            bf16x8 a  = *(const bf16x8*)(aBase + k0);
            bf16x8 b0 = *(const bf16x8*)(b0Base + k0);
            bf16x8 b1 = *(const bf16x8*)(b1Base + k0);
            cB0 = __builtin_amdgcn_mfma_f32_16x16x32_bf16(a, b0, cB0, 0, 0, 0);
            cB1 = __builtin_amdgcn_mfma_f32_16x16x32_bf16(a, b1, cB1, 0, 0, 0);
        }
    }
    // epilogue: outer relu; write h (bf16) or pool atomics (f32)
    #pragma unroll
    for (int r = 0; r < 4; r++) {
        int row = q * 4 + r;
        int node = node0 + row;
        float v0 = cB0[r] > 0.f ? cB0[r] : 0.f;
        float v1 = cB1[r] > 0.f ? cB1[r] : 0.f;
        if (POOL) {
            int g = batch[node];
            atomicAdd(&((float*)outv)[g * HID + n0 + i16], v0);
            atomicAdd(&((float*)outv)[g * HID + n1 + i16], v1);
        } else {
            ((unsigned short*)outv)[(size_t)node * HID + n0 + i16] = f2bf(v0);
            ((unsigned short*)outv)[(size_t)node * HID + n1 + i16] = f2bf(v1);
        }
    }
}

// ---------------------------------------------------------------------------
// Pool mean: batch is SORTED -> count[g] by binary search (wave-uniform).
// ---------------------------------------------------------------------------
__global__ void pool_div_kernel(const float* __restrict__ sums,
                                const int* __restrict__ batch,
                                float* __restrict__ out) {
    int i = blockIdx.x * blockDim.x + threadIdx.x;
    if (i >= N_GRAPHS * HID) return;
    int g = i / HID;
    int lo = 0, hi = N_NODES;
    while (lo < hi) { int mid = (lo + hi) >> 1; if (batch[mid] < g) lo = mid + 1; else hi = mid; }
    int start = lo;
    lo = 0; hi = N_NODES;
    while (lo < hi) { int mid = (lo + hi) >> 1; if (batch[mid] <= g) lo = mid + 1; else hi = mid; }
    float c = (float)(lo - start);
    out[i] = sums[i] / (c > 1.0f ? c : 1.0f);
}

extern "C" void kernel_launch(void* const* d_in, const int* in_sizes, int n_in,
                              void* d_out, int out_size, void* d_ws, size_t ws_size,
                              hipStream_t stream) {
    const float* x    = (const float*)d_in[0];
    const int*   ei   = (const int*)d_in[1];
    const float* ea   = (const float*)d_in[2];
    const int*   batch= (const int*)d_in[3];
    const float* el1w = (const float*)d_in[4];
    const float* el1b = (const float*)d_in[5];
    const float* w1a  = (const float*)d_in[6];
    const float* b1a  = (const float*)d_in[7];
    const float* w1b  = (const float*)d_in[8];
    const float* b1b  = (const float*)d_in[9];
    const float* el2w = (const float*)d_in[10];
    const float* el2b = (const float*)d_in[11];
    const float* w2a  = (const float*)d_in[12];
    const float* b2a  = (const float*)d_in[13];
    const float* w2b  = (const float*)d_in[14];
    const float* b2b  = (const float*)d_in[15];
    float* out = (float*)d_out;

    // workspace layout (16B-aligned sections)
    int4* edata = (int4*)d_ws;                               // [E] {src,a0,a1,a2}
    float* psum = (float*)(edata + N_EDGES);                 // [G*HID]   8192 f32
    int* deg    = (int*)(psum + N_GRAPHS * HID);             // [N]
    int* cursor = deg + N_NODES;                             // [N]
    int* rowptr = cursor + N_NODES;                          // [N+1]
    // 8192+50000+50000+50001 = 158193 ints; pad 3 -> 158196 (x4 = 16B multiple)
    unsigned short* xbf  = (unsigned short*)(((char*)psum) + (size_t)158196 * 4 - 0);
    xbf = (unsigned short*)((char*)psum + (size_t)158196 * 4);
    unsigned short* hbf  = xbf + (size_t)N_NODES * IN_CH;    // bf16 [N, HID]
    unsigned short* waT1 = hbf + (size_t)N_NODES * HID;      // bf16 [128, 64]
    unsigned short* wbT1 = waT1 + HID * IN_CH;               // bf16 [128, 128]
    unsigned short* waT2 = wbT1 + HID * HID;                 // bf16 [128, 128]
    unsigned short* wbT2 = waT2 + HID * HID;                 // bf16 [128, 128]

    // ---- prep: CSR build, x->bf16, weight transpose+bf16 ----
    hipMemsetAsync(deg, 0, N_NODES * sizeof(int), stream);
    hist_kernel<<<(N_EDGES + 255) / 256, 256, 0, stream>>>(ei, deg);
    cvt_kernel<<<(N_NODES * IN_CH + 255) / 256, 256, 0, stream>>>(x, xbf, N_NODES * IN_CH);
    tw_kernel<<<(IN_CH * HID + 255) / 256, 256, 0, stream>>>(w1a, waT1, IN_CH, HID);
    tw_kernel<<<(HID * HID + 255) / 256, 256, 0, stream>>>(w1b, wbT1, HID, HID);
    tw_kernel<<<(HID * HID + 255) / 256, 256, 0, stream>>>(w2a, waT2, HID, HID);
    tw_kernel<<<(HID * HID + 255) / 256, 256, 0, stream>>>(w2b, wbT2, HID, HID);
    scan_kernel<<<1, 1024, 0, stream>>>(deg, rowptr, cursor);
    scatter_kernel<<<(N_EDGES + 255) / 256, 256, 0, stream>>>(ei, ea, cursor, edata);

    // ---- layer 1: gather + MFMA MLP -> hbf ----
    fused_layer<IN_CH, false><<<N_NODES / 16, 256, 0, stream>>>(
        xbf, edata, rowptr, el1w, el1b, waT1, b1a, wbT1, b1b, hbf, nullptr);

    // ---- layer 2: gather + MFMA MLP + pool atomics ----
    hipMemsetAsync(psum, 0, N_GRAPHS * HID * sizeof(float), stream);
    fused_layer<HID, true><<<N_NODES / 16, 256, 0, stream>>>(
        hbf, edata, rowptr, el2w, el2b, waT2, b2a, wbT2, b2b, psum, batch);

    // ---- mean (count via binary search on sorted batch) ----
    pool_div_kernel<<<(N_GRAPHS * HID + 255) / 256, 256, 0, stream>>>(psum, batch, out);
}

// Round 7
// 483.367 us; speedup vs baseline: 1.2759x; 1.2759x over previous
//
#include <hip/hip_runtime.h>

#define N_NODES 50000
#define N_EDGES 600000
#define IN_CH 64
#define HID 128
#define N_GRAPHS 64

// ---- bf16 helpers (manual, RNE) ----
__device__ __forceinline__ float bf2f(unsigned short u) {
    union { unsigned int i; float f; } v; v.i = ((unsigned int)u) << 16; return v.f;
}
__device__ __forceinline__ unsigned short f2bf(float f) {
    union { float f; unsigned int i; } v; v.f = f;
    unsigned int u = v.i;
    return (unsigned short)((u + 0x7FFFu + ((u >> 16) & 1u)) >> 16);
}
__device__ __forceinline__ float rowval(float f) { return f; }
__device__ __forceinline__ float rowval(unsigned short u) { return bf2f(u); }

template <bool B> struct RowType { using T = float; };
template <> struct RowType<true> { using T = unsigned short; };

// ===========================================================================
// CSR build: counting-sort edges by dst; edata[pos] = {src, a0, a1, a2}.
// ===========================================================================
__global__ void hist_kernel(const int* __restrict__ ei, int* __restrict__ deg) {
    int e = blockIdx.x * blockDim.x + threadIdx.x;
    if (e < N_EDGES) atomicAdd(&deg[ei[N_EDGES + e]], 1);
}

// Single-block scan: serial local sum -> 1024-wide LDS scan -> serial write.
__global__ void scan_kernel(const int* __restrict__ deg,
                            int* __restrict__ rowptr,
                            int* __restrict__ cursor) {
    __shared__ int partial[1024];
    const int t = threadIdx.x;
    const int CHUNK = (N_NODES + 1023) / 1024;  // 49
    int begin = t * CHUNK;
    int end = begin + CHUNK; if (end > N_NODES) end = N_NODES;
    int sum = 0;
    for (int i = begin; i < end; i++) sum += deg[i];
    int val = sum;
    partial[t] = val;
    __syncthreads();
    for (int off = 1; off < 1024; off <<= 1) {
        int n = (t >= off) ? partial[t - off] : 0;
        __syncthreads();
        val += n;
        partial[t] = val;
        __syncthreads();
    }
    int run = val - sum;
    for (int i = begin; i < end; i++) { rowptr[i] = run; cursor[i] = run; run += deg[i]; }
    if (t == 1023) rowptr[N_NODES] = run;
}

__global__ void scatter_kernel(const int* __restrict__ ei,
                               const float* __restrict__ ea,
                               int* __restrict__ cursor,
                               int4* __restrict__ edata) {
    int e = blockIdx.x * blockDim.x + threadIdx.x;
    if (e < N_EDGES) {
        int dst = ei[N_EDGES + e];
        int pos = atomicAdd(&cursor[dst], 1);
        edata[pos] = make_int4(ei[e],
                               __float_as_int(ea[3 * e]),
                               __float_as_int(ea[3 * e + 1]),
                               __float_as_int(ea[3 * e + 2]));
    }
}

// ===========================================================================
// Fused GINE layer — R4/R5 proven structure: 128 threads, NPB=8 nodes/block.
//   sIn = x[n] + sum_{e: dst(e)=n} relu(x[src(e)] + ea[e]@elw + elb)
//   out = relu( relu(sIn@wa+ba) @ wb + bb )
// XBF: node features are bf16 (layer 2) vs f32 (layer 1 — bf16 unpack hurt
// the VALU-bound K=64 layer in R5, so layer 1 stays f32).
// HOUT: write h as bf16 (halves h traffic, feeds layer-2 gather).
// POOL: f32 atomics into per-graph pool sums.
// Edge loop unrolled x8 (+4 +1 tails): 8 row gathers in flight per wave.
// ===========================================================================
template <int K, int NPB, bool XBF, bool POOL>
__global__ void fused_layer(const void* __restrict__ xinv,
                            const int4* __restrict__ edata,
                            const int* __restrict__ rowptr,
                            const float* __restrict__ elw,  // [3, K]
                            const float* __restrict__ elb,  // [K]
                            const float* __restrict__ wa,   // [K, HID]
                            const float* __restrict__ ba,
                            const float* __restrict__ wb,   // [HID, HID]
                            const float* __restrict__ bb,
                            void* __restrict__ outv,        // bf16 h [N,HID] or f32 psum
                            const int* __restrict__ batch) {
    using RowT = typename RowType<XBF>::T;
    const RowT* __restrict__ xin = (const RowT*)xinv;
    __shared__ float sIn[NPB][K];
    __shared__ float sHid[NPB][HID];
    const int node0 = blockIdx.x * NPB;
    const int t = threadIdx.x;  // 0..127

    // ---- aggregation (gather over CSR, 8 rows in flight) ----
    {
        const int c = (K == 128) ? t : (t & 63);
        const int half = (K == 128) ? 0 : (t >> 6);
        const int istep = (K == 128) ? 1 : 2;
        const float w0 = elw[c], w1 = elw[K + c], w2 = elw[2 * K + c], eb = elb[c];

        auto term = [&](int4 e, RowT row) -> float {
            float ev = __int_as_float(e.y) * w0 + __int_as_float(e.z) * w1 +
                       __int_as_float(e.w) * w2 + eb;
            float m = rowval(row) + ev;
            return m > 0.f ? m : 0.f;
        };

        for (int i = 0; i < NPB; i += istep) {
            int node = node0 + i + half;
            float acc = rowval(xin[(size_t)node * K + c]);
            int jb = rowptr[node], je = rowptr[node + 1];
            int j = jb;
            for (; j + 8 <= je; j += 8) {
                int4 e0 = edata[j],     e1 = edata[j + 1], e2 = edata[j + 2], e3 = edata[j + 3];
                int4 e4 = edata[j + 4], e5 = edata[j + 5], e6 = edata[j + 6], e7 = edata[j + 7];
                RowT r0 = xin[(size_t)e0.x * K + c];
                RowT r1 = xin[(size_t)e1.x * K + c];
                RowT r2 = xin[(size_t)e2.x * K + c];
                RowT r3 = xin[(size_t)e3.x * K + c];
                RowT r4 = xin[(size_t)e4.x * K + c];
                RowT r5 = xin[(size_t)e5.x * K + c];
                RowT r6 = xin[(size_t)e6.x * K + c];
                RowT r7 = xin[(size_t)e7.x * K + c];
                acc += term(e0, r0) + term(e1, r1) + term(e2, r2) + term(e3, r3)
                     + term(e4, r4) + term(e5, r5) + term(e6, r6) + term(e7, r7);
            }
            for (; j + 4 <= je; j += 4) {
                int4 e0 = edata[j], e1 = edata[j + 1], e2 = edata[j + 2], e3 = edata[j + 3];
                RowT r0 = xin[(size_t)e0.x * K + c];
                RowT r1 = xin[(size_t)e1.x * K + c];
                RowT r2 = xin[(size_t)e2.x * K + c];
                RowT r3 = xin[(size_t)e3.x * K + c];
                acc += term(e0, r0) + term(e1, r1) + term(e2, r2) + term(e3, r3);
            }
            for (; j < je; j++) {
                int4 e0 = edata[j];
                acc += term(e0, xin[(size_t)e0.x * K + c]);
            }
            sIn[i + half][c] = acc;
        }
    }
    __syncthreads();

    // ---- MLP layer A: sHid = relu(sIn @ wa + ba) ----
    float acc[NPB];
    #pragma unroll
    for (int i = 0; i < NPB; i++) acc[i] = ba[t];
    for (int k = 0; k < K; k++) {
        float w = wa[k * HID + t];
        #pragma unroll
        for (int i = 0; i < NPB; i++) acc[i] += sIn[i][k] * w;
    }
    #pragma unroll
    for (int i = 0; i < NPB; i++) sHid[i][t] = acc[i] > 0.f ? acc[i] : 0.f;
    __syncthreads();

    // ---- MLP layer B + outer relu ----
    float acc2[NPB];
    #pragma unroll
    for (int i = 0; i < NPB; i++) acc2[i] = bb[t];
    for (int k = 0; k < HID; k++) {
        float w = wb[k * HID + t];
        #pragma unroll
        for (int i = 0; i < NPB; i++) acc2[i] += sHid[i][k] * w;
    }
    #pragma unroll
    for (int i = 0; i < NPB; i++) {
        int node = node0 + i;
        float v = acc2[i] > 0.f ? acc2[i] : 0.f;
        if (POOL) {
            atomicAdd(&((float*)outv)[batch[node] * HID + t], v);
        } else {
            ((unsigned short*)outv)[(size_t)node * HID + t] = f2bf(v);
        }
    }
}

// ---------------------------------------------------------------------------
// Pool mean: batch is SORTED -> count[g] by binary search (wave-uniform).
// ---------------------------------------------------------------------------
__global__ void pool_div_kernel(const float* __restrict__ sums,
                                const int* __restrict__ batch,
                                float* __restrict__ out) {
    int i = blockIdx.x * blockDim.x + threadIdx.x;
    if (i >= N_GRAPHS * HID) return;
    int g = i / HID;
    int lo = 0, hi = N_NODES;
    while (lo < hi) { int mid = (lo + hi) >> 1; if (batch[mid] < g) lo = mid + 1; else hi = mid; }
    int start = lo;
    lo = 0; hi = N_NODES;
    while (lo < hi) { int mid = (lo + hi) >> 1; if (batch[mid] <= g) lo = mid + 1; else hi = mid; }
    float c = (float)(lo - start);
    out[i] = sums[i] / (c > 1.0f ? c : 1.0f);
}

extern "C" void kernel_launch(void* const* d_in, const int* in_sizes, int n_in,
                              void* d_out, int out_size, void* d_ws, size_t ws_size,
                              hipStream_t stream) {
    const float* x    = (const float*)d_in[0];
    const int*   ei   = (const int*)d_in[1];
    const float* ea   = (const float*)d_in[2];
    const int*   batch= (const int*)d_in[3];
    const float* el1w = (const float*)d_in[4];
    const float* el1b = (const float*)d_in[5];
    const float* w1a  = (const float*)d_in[6];
    const float* b1a  = (const float*)d_in[7];
    const float* w1b  = (const float*)d_in[8];
    const float* b1b  = (const float*)d_in[9];
    const float* el2w = (const float*)d_in[10];
    const float* el2b = (const float*)d_in[11];
    const float* w2a  = (const float*)d_in[12];
    const float* b2a  = (const float*)d_in[13];
    const float* w2b  = (const float*)d_in[14];
    const float* b2b  = (const float*)d_in[15];
    float* out = (float*)d_out;

    // workspace layout (16B-aligned sections)
    int4*  edata  = (int4*)d_ws;                     // [E] {src,a0,a1,a2}
    float* psum   = (float*)(edata + N_EDGES);       // [G*HID] 8192 f32
    int*   deg    = (int*)(psum + N_GRAPHS * HID);   // [N]
    int*   cursor = deg + N_NODES;                   // [N]
    int*   rowptr = cursor + N_NODES;                // [N+1]
    // ints so far: 8192+50000+50000+50001 = 158193; pad to 158196 (16B mult)
    unsigned short* hbf = (unsigned short*)((char*)psum + (size_t)158196 * 4);  // bf16 [N, HID]

    // ---- prep: CSR build ----
    hipMemsetAsync(deg, 0, N_NODES * sizeof(int), stream);
    hist_kernel<<<(N_EDGES + 255) / 256, 256, 0, stream>>>(ei, deg);
    scan_kernel<<<1, 1024, 0, stream>>>(deg, rowptr, cursor);
    scatter_kernel<<<(N_EDGES + 255) / 256, 256, 0, stream>>>(ei, ea, cursor, edata);

    // ---- layer 1: f32 gather (R4-proven) + f32 MLP, h out as bf16 ----
    fused_layer<IN_CH, 8, false, false><<<N_NODES / 8, 128, 0, stream>>>(
        x, edata, rowptr, el1w, el1b, w1a, b1a, w1b, b1b, hbf, nullptr);

    // ---- layer 2: bf16 gather (R5-proven) + f32 MLP + pool atomics ----
    hipMemsetAsync(psum, 0, N_GRAPHS * HID * sizeof(float), stream);
    fused_layer<HID, 8, true, true><<<N_NODES / 8, 128, 0, stream>>>(
        hbf, edata, rowptr, el2w, el2b, w2a, b2a, w2b, b2b, psum, batch);

    // ---- mean (count via binary search on sorted batch) ----
    pool_div_kernel<<<(N_GRAPHS * HID + 255) / 256, 256, 0, stream>>>(psum, batch, out);
}

// Round 8
// 422.741 us; speedup vs baseline: 1.4589x; 1.1434x over previous
//
#include <hip/hip_runtime.h>

#define N_NODES 50000
#define N_EDGES 600000
#define IN_CH 64
#define HID 128
#define N_GRAPHS 64
#define SCAN_BLOCKS 196   // ceil(N_NODES/256)

// ---- bf16 helpers (manual, RNE) ----
__device__ __forceinline__ float bf2f(unsigned short u) {
    union { unsigned int i; float f; } v; v.i = ((unsigned int)u) << 16; return v.f;
}
__device__ __forceinline__ unsigned short f2bf(float f) {
    union { float f; unsigned int i; } v; v.f = f;
    unsigned int u = v.i;
    return (unsigned short)((u + 0x7FFFu + ((u >> 16) & 1u)) >> 16);
}
__device__ __forceinline__ float rowval(float f) { return f; }
__device__ __forceinline__ float rowval(unsigned short u) { return bf2f(u); }

template <bool B> struct RowType { using T = float; };
template <> struct RowType<true> { using T = unsigned short; };

// ===========================================================================
// CSR build: counting-sort edges by dst; edata[pos] = {src, a0, a1, a2}.
// Scan is now 3 parallel kernels (R7's single-block scan = one CU serial).
// ===========================================================================
__global__ void hist_kernel(const int* __restrict__ ei, int* __restrict__ deg) {
    int e = blockIdx.x * blockDim.x + threadIdx.x;
    if (e < N_EDGES) atomicAdd(&deg[ei[N_EDGES + e]], 1);
}

__device__ __forceinline__ int block_incl_scan256(int v, int* sm, int t) {
    int val = v;
    sm[t] = val; __syncthreads();
    #pragma unroll
    for (int off = 1; off < 256; off <<= 1) {
        int n = (t >= off) ? sm[t - off] : 0;
        __syncthreads();
        val += n; sm[t] = val; __syncthreads();
    }
    return val;
}

// per-block sums of deg
__global__ void scan1_kernel(const int* __restrict__ deg, int* __restrict__ partials) {
    __shared__ int sm[256];
    int t = threadIdx.x;
    int i = blockIdx.x * 256 + t;
    int v = (i < N_NODES) ? deg[i] : 0;
    sm[t] = v; __syncthreads();
    for (int off = 128; off > 0; off >>= 1) {
        if (t < off) sm[t] += sm[t + off];
        __syncthreads();
    }
    if (t == 0) partials[blockIdx.x] = sm[0];
}

// exclusive scan of the 196 partials, in place
__global__ void scan2_kernel(int* __restrict__ partials) {
    __shared__ int sm[256];
    int t = threadIdx.x;
    int v = (t < SCAN_BLOCKS) ? partials[t] : 0;
    int incl = block_incl_scan256(v, sm, t);
    if (t < SCAN_BLOCKS) partials[t] = incl - v;
}

// full exclusive scan: in-block scan + partial offset -> rowptr & cursor
__global__ void scan3_kernel(const int* __restrict__ deg,
                             const int* __restrict__ partials,
                             int* __restrict__ rowptr,
                             int* __restrict__ cursor) {
    __shared__ int sm[256];
    int t = threadIdx.x;
    int i = blockIdx.x * 256 + t;
    int v = (i < N_NODES) ? deg[i] : 0;
    int incl = block_incl_scan256(v, sm, t);
    int excl = incl - v + partials[blockIdx.x];
    if (i < N_NODES) { rowptr[i] = excl; cursor[i] = excl; }
    if (blockIdx.x == 0 && t == 0) rowptr[N_NODES] = N_EDGES;
}

__global__ void scatter_kernel(const int* __restrict__ ei,
                               const float* __restrict__ ea,
                               int* __restrict__ cursor,
                               int4* __restrict__ edata) {
    int e = blockIdx.x * blockDim.x + threadIdx.x;
    if (e < N_EDGES) {
        int dst = ei[N_EDGES + e];
        int pos = atomicAdd(&cursor[dst], 1);
        edata[pos] = make_int4(ei[e],
                               __float_as_int(ea[3 * e]),
                               __float_as_int(ea[3 * e + 1]),
                               __float_as_int(ea[3 * e + 2]));
    }
}

// ===========================================================================
// Fused GINE layer — R7 structure: 128 threads, NPB=8 nodes/block.
// Gather phase byte-identical to R7 (proven). MLP loops now read sIn/sHid
// as float4 (broadcast ds_read_b128, ~2x fewer LDS issue cycles).
// ===========================================================================
template <int K, int NPB, bool XBF, bool POOL>
__global__ void fused_layer(const void* __restrict__ xinv,
                            const int4* __restrict__ edata,
                            const int* __restrict__ rowptr,
                            const float* __restrict__ elw,  // [3, K]
                            const float* __restrict__ elb,  // [K]
                            const float* __restrict__ wa,   // [K, HID]
                            const float* __restrict__ ba,
                            const float* __restrict__ wb,   // [HID, HID]
                            const float* __restrict__ bb,
                            void* __restrict__ outv,        // bf16 h [N,HID] or f32 psum
                            const int* __restrict__ batch) {
    using RowT = typename RowType<XBF>::T;
    const RowT* __restrict__ xin = (const RowT*)xinv;
    __shared__ __align__(16) float sIn[NPB][K];
    __shared__ __align__(16) float sHid[NPB][HID];
    const int node0 = blockIdx.x * NPB;
    const int t = threadIdx.x;  // 0..127

    // ---- aggregation (gather over CSR, 8 rows in flight) — R7-identical ----
    {
        const int c = (K == 128) ? t : (t & 63);
        const int half = (K == 128) ? 0 : (t >> 6);
        const int istep = (K == 128) ? 1 : 2;
        const float w0 = elw[c], w1 = elw[K + c], w2 = elw[2 * K + c], eb = elb[c];

        auto term = [&](int4 e, RowT row) -> float {
            float ev = __int_as_float(e.y) * w0 + __int_as_float(e.z) * w1 +
                       __int_as_float(e.w) * w2 + eb;
            float m = rowval(row) + ev;
            return m > 0.f ? m : 0.f;
        };

        for (int i = 0; i < NPB; i += istep) {
            int node = node0 + i + half;
            float acc = rowval(xin[(size_t)node * K + c]);
            int jb = rowptr[node], je = rowptr[node + 1];
            int j = jb;
            for (; j + 8 <= je; j += 8) {
                int4 e0 = edata[j],     e1 = edata[j + 1], e2 = edata[j + 2], e3 = edata[j + 3];
                int4 e4 = edata[j + 4], e5 = edata[j + 5], e6 = edata[j + 6], e7 = edata[j + 7];
                RowT r0 = xin[(size_t)e0.x * K + c];
                RowT r1 = xin[(size_t)e1.x * K + c];
                RowT r2 = xin[(size_t)e2.x * K + c];
                RowT r3 = xin[(size_t)e3.x * K + c];
                RowT r4 = xin[(size_t)e4.x * K + c];
                RowT r5 = xin[(size_t)e5.x * K + c];
                RowT r6 = xin[(size_t)e6.x * K + c];
                RowT r7 = xin[(size_t)e7.x * K + c];
                acc += term(e0, r0) + term(e1, r1) + term(e2, r2) + term(e3, r3)
                     + term(e4, r4) + term(e5, r5) + term(e6, r6) + term(e7, r7);
            }
            for (; j + 4 <= je; j += 4) {
                int4 e0 = edata[j], e1 = edata[j + 1], e2 = edata[j + 2], e3 = edata[j + 3];
                RowT r0 = xin[(size_t)e0.x * K + c];
                RowT r1 = xin[(size_t)e1.x * K + c];
                RowT r2 = xin[(size_t)e2.x * K + c];
                RowT r3 = xin[(size_t)e3.x * K + c];
                acc += term(e0, r0) + term(e1, r1) + term(e2, r2) + term(e3, r3);
            }
            for (; j < je; j++) {
                int4 e0 = edata[j];
                acc += term(e0, xin[(size_t)e0.x * K + c]);
            }
            sIn[i + half][c] = acc;
        }
    }
    __syncthreads();

    // ---- MLP layer A: sHid = relu(sIn @ wa + ba), float4 LDS reads ----
    float acc[NPB];
    #pragma unroll
    for (int i = 0; i < NPB; i++) acc[i] = ba[t];
    for (int k = 0; k < K; k += 4) {
        float wk0 = wa[k * HID + t];
        float wk1 = wa[(k + 1) * HID + t];
        float wk2 = wa[(k + 2) * HID + t];
        float wk3 = wa[(k + 3) * HID + t];
        #pragma unroll
        for (int i = 0; i < NPB; i++) {
            float4 s = *(const float4*)&sIn[i][k];
            acc[i] += s.x * wk0 + s.y * wk1 + s.z * wk2 + s.w * wk3;
        }
    }
    #pragma unroll
    for (int i = 0; i < NPB; i++) sHid[i][t] = acc[i] > 0.f ? acc[i] : 0.f;
    __syncthreads();

    // ---- MLP layer B + outer relu, float4 LDS reads ----
    float acc2[NPB];
    #pragma unroll
    for (int i = 0; i < NPB; i++) acc2[i] = bb[t];
    for (int k = 0; k < HID; k += 4) {
        float wk0 = wb[k * HID + t];
        float wk1 = wb[(k + 1) * HID + t];
        float wk2 = wb[(k + 2) * HID + t];
        float wk3 = wb[(k + 3) * HID + t];
        #pragma unroll
        for (int i = 0; i < NPB; i++) {
            float4 s = *(const float4*)&sHid[i][k];
            acc2[i] += s.x * wk0 + s.y * wk1 + s.z * wk2 + s.w * wk3;
        }
    }
    #pragma unroll
    for (int i = 0; i < NPB; i++) {
        int node = node0 + i;
        float v = acc2[i] > 0.f ? acc2[i] : 0.f;
        if (POOL) {
            atomicAdd(&((float*)outv)[batch[node] * HID + t], v);
        } else {
            ((unsigned short*)outv)[(size_t)node * HID + t] = f2bf(v);
        }
    }
}

// ---------------------------------------------------------------------------
// Pool mean: batch is SORTED -> count[g] by binary search (wave-uniform).
// ---------------------------------------------------------------------------
__global__ void pool_div_kernel(const float* __restrict__ sums,
                                const int* __restrict__ batch,
                                float* __restrict__ out) {
    int i = blockIdx.x * blockDim.x + threadIdx.x;
    if (i >= N_GRAPHS * HID) return;
    int g = i / HID;
    int lo = 0, hi = N_NODES;
    while (lo < hi) { int mid = (lo + hi) >> 1; if (batch[mid] < g) lo = mid + 1; else hi = mid; }
    int start = lo;
    lo = 0; hi = N_NODES;
    while (lo < hi) { int mid = (lo + hi) >> 1; if (batch[mid] <= g) lo = mid + 1; else hi = mid; }
    float c = (float)(lo - start);
    out[i] = sums[i] / (c > 1.0f ? c : 1.0f);
}

extern "C" void kernel_launch(void* const* d_in, const int* in_sizes, int n_in,
                              void* d_out, int out_size, void* d_ws, size_t ws_size,
                              hipStream_t stream) {
    const float* x    = (const float*)d_in[0];
    const int*   ei   = (const int*)d_in[1];
    const float* ea   = (const float*)d_in[2];
    const int*   batch= (const int*)d_in[3];
    const float* el1w = (const float*)d_in[4];
    const float* el1b = (const float*)d_in[5];
    const float* w1a  = (const float*)d_in[6];
    const float* b1a  = (const float*)d_in[7];
    const float* w1b  = (const float*)d_in[8];
    const float* b1b  = (const float*)d_in[9];
    const float* el2w = (const float*)d_in[10];
    const float* el2b = (const float*)d_in[11];
    const float* w2a  = (const float*)d_in[12];
    const float* b2a  = (const float*)d_in[13];
    const float* w2b  = (const float*)d_in[14];
    const float* b2b  = (const float*)d_in[15];
    float* out = (float*)d_out;

    // workspace layout (16B-aligned sections)
    int4*  edata    = (int4*)d_ws;                      // [E] {src,a0,a1,a2}
    float* psum     = (float*)(edata + N_EDGES);        // [G*HID] 8192 f32
    int*   deg      = (int*)(psum + N_GRAPHS * HID);    // [N]
    int*   cursor   = deg + N_NODES;                    // [N]
    int*   rowptr   = cursor + N_NODES;                 // [N+1]
    int*   partials = rowptr + N_NODES + 1;             // [256]
    // ints so far: 8192+50000+50000+50001+256 = 158449; pad to 158452 (16B mult)
    unsigned short* hbf = (unsigned short*)((char*)psum + (size_t)158452 * 4);  // bf16 [N,HID]

    // ---- prep: CSR build (parallel scan) ----
    hipMemsetAsync(deg, 0, N_NODES * sizeof(int), stream);
    hist_kernel<<<(N_EDGES + 255) / 256, 256, 0, stream>>>(ei, deg);
    scan1_kernel<<<SCAN_BLOCKS, 256, 0, stream>>>(deg, partials);
    scan2_kernel<<<1, 256, 0, stream>>>(partials);
    scan3_kernel<<<SCAN_BLOCKS, 256, 0, stream>>>(deg, partials, rowptr, cursor);
    scatter_kernel<<<(N_EDGES + 255) / 256, 256, 0, stream>>>(ei, ea, cursor, edata);

    // ---- layer 1: f32 gather + f32 MLP (float4 LDS), h out as bf16 ----
    fused_layer<IN_CH, 8, false, false><<<N_NODES / 8, 128, 0, stream>>>(
        x, edata, rowptr, el1w, el1b, w1a, b1a, w1b, b1b, hbf, nullptr);

    // ---- layer 2: bf16 gather + f32 MLP (float4 LDS) + pool atomics ----
    hipMemsetAsync(psum, 0, N_GRAPHS * HID * sizeof(float), stream);
    fused_layer<HID, 8, true, true><<<N_NODES / 8, 128, 0, stream>>>(
        hbf, edata, rowptr, el2w, el2b, w2a, b2a, w2b, b2b, psum, batch);

    // ---- mean (count via binary search on sorted batch) ----
    pool_div_kernel<<<(N_GRAPHS * HID + 255) / 256, 256, 0, stream>>>(psum, batch, out);
}

// Round 9
// 388.429 us; speedup vs baseline: 1.5877x; 1.0883x over previous
//
#include <hip/hip_runtime.h>

#define N_NODES 50000
#define N_EDGES 600000
#define IN_CH 64
#define HID 128
#define N_GRAPHS 64
#define SCAN_BLOCKS 196   // ceil(N_NODES/256)

// ---- bf16 helpers (manual, RNE) ----
__device__ __forceinline__ float bf2f(unsigned short u) {
    union { unsigned int i; float f; } v; v.i = ((unsigned int)u) << 16; return v.f;
}
__device__ __forceinline__ unsigned short f2bf(float f) {
    union { float f; unsigned int i; } v; v.f = f;
    unsigned int u = v.i;
    return (unsigned short)((u + 0x7FFFu + ((u >> 16) & 1u)) >> 16);
}
__device__ __forceinline__ float rowval(float f) { return f; }
__device__ __forceinline__ float rowval(unsigned short u) { return bf2f(u); }

template <bool B> struct RowType { using T = float; };
template <> struct RowType<true> { using T = unsigned short; };

// ===========================================================================
// CSR build: counting-sort edges by dst; edata[pos] = {src, a0, a1, a2}.
// Parallel 3-kernel scan (R8-proven: removed ~100us of single-CU serial scan).
// ===========================================================================
__global__ void hist_kernel(const int* __restrict__ ei, int* __restrict__ deg) {
    int e = blockIdx.x * blockDim.x + threadIdx.x;
    if (e < N_EDGES) atomicAdd(&deg[ei[N_EDGES + e]], 1);
}

__device__ __forceinline__ int block_incl_scan256(int v, int* sm, int t) {
    int val = v;
    sm[t] = val; __syncthreads();
    #pragma unroll
    for (int off = 1; off < 256; off <<= 1) {
        int n = (t >= off) ? sm[t - off] : 0;
        __syncthreads();
        val += n; sm[t] = val; __syncthreads();
    }
    return val;
}

__global__ void scan1_kernel(const int* __restrict__ deg, int* __restrict__ partials) {
    __shared__ int sm[256];
    int t = threadIdx.x;
    int i = blockIdx.x * 256 + t;
    int v = (i < N_NODES) ? deg[i] : 0;
    sm[t] = v; __syncthreads();
    for (int off = 128; off > 0; off >>= 1) {
        if (t < off) sm[t] += sm[t + off];
        __syncthreads();
    }
    if (t == 0) partials[blockIdx.x] = sm[0];
}

__global__ void scan2_kernel(int* __restrict__ partials) {
    __shared__ int sm[256];
    int t = threadIdx.x;
    int v = (t < SCAN_BLOCKS) ? partials[t] : 0;
    int incl = block_incl_scan256(v, sm, t);
    if (t < SCAN_BLOCKS) partials[t] = incl - v;
}

__global__ void scan3_kernel(const int* __restrict__ deg,
                             const int* __restrict__ partials,
                             int* __restrict__ rowptr,
                             int* __restrict__ cursor) {
    __shared__ int sm[256];
    int t = threadIdx.x;
    int i = blockIdx.x * 256 + t;
    int v = (i < N_NODES) ? deg[i] : 0;
    int incl = block_incl_scan256(v, sm, t);
    int excl = incl - v + partials[blockIdx.x];
    if (i < N_NODES) { rowptr[i] = excl; cursor[i] = excl; }
    if (blockIdx.x == 0 && t == 0) rowptr[N_NODES] = N_EDGES;
}

__global__ void scatter_kernel(const int* __restrict__ ei,
                               const float* __restrict__ ea,
                               int* __restrict__ cursor,
                               int4* __restrict__ edata) {
    int e = blockIdx.x * blockDim.x + threadIdx.x;
    if (e < N_EDGES) {
        int dst = ei[N_EDGES + e];
        int pos = atomicAdd(&cursor[dst], 1);
        edata[pos] = make_int4(ei[e],
                               __float_as_int(ea[3 * e]),
                               __float_as_int(ea[3 * e + 1]),
                               __float_as_int(ea[3 * e + 2]));
    }
}

// ===========================================================================
// Fused GINE layer — R7-proven structure, byte-identical: 128 threads,
// NPB=8 nodes/block, scalar MLP loops (VGPR 32, occ ~65%).
// [R8 lesson: float4 LDS reads in the MLP -> VGPR 48, occ 46%, +30us. The
// gather is latency-bound and lives on occupancy; do not re-add.]
// ===========================================================================
template <int K, int NPB, bool XBF, bool POOL>
__global__ void fused_layer(const void* __restrict__ xinv,
                            const int4* __restrict__ edata,
                            const int* __restrict__ rowptr,
                            const float* __restrict__ elw,  // [3, K]
                            const float* __restrict__ elb,  // [K]
                            const float* __restrict__ wa,   // [K, HID]
                            const float* __restrict__ ba,
                            const float* __restrict__ wb,   // [HID, HID]
                            const float* __restrict__ bb,
                            void* __restrict__ outv,        // bf16 h [N,HID] or f32 psum
                            const int* __restrict__ batch) {
    using RowT = typename RowType<XBF>::T;
    const RowT* __restrict__ xin = (const RowT*)xinv;
    __shared__ float sIn[NPB][K];
    __shared__ float sHid[NPB][HID];
    const int node0 = blockIdx.x * NPB;
    const int t = threadIdx.x;  // 0..127

    // ---- aggregation (gather over CSR, 8 rows in flight) ----
    {
        const int c = (K == 128) ? t : (t & 63);
        const int half = (K == 128) ? 0 : (t >> 6);
        const int istep = (K == 128) ? 1 : 2;
        const float w0 = elw[c], w1 = elw[K + c], w2 = elw[2 * K + c], eb = elb[c];

        auto term = [&](int4 e, RowT row) -> float {
            float ev = __int_as_float(e.y) * w0 + __int_as_float(e.z) * w1 +
                       __int_as_float(e.w) * w2 + eb;
            float m = rowval(row) + ev;
            return m > 0.f ? m : 0.f;
        };

        for (int i = 0; i < NPB; i += istep) {
            int node = node0 + i + half;
            float acc = rowval(xin[(size_t)node * K + c]);
            int jb = rowptr[node], je = rowptr[node + 1];
            int j = jb;
            for (; j + 8 <= je; j += 8) {
                int4 e0 = edata[j],     e1 = edata[j + 1], e2 = edata[j + 2], e3 = edata[j + 3];
                int4 e4 = edata[j + 4], e5 = edata[j + 5], e6 = edata[j + 6], e7 = edata[j + 7];
                RowT r0 = xin[(size_t)e0.x * K + c];
                RowT r1 = xin[(size_t)e1.x * K + c];
                RowT r2 = xin[(size_t)e2.x * K + c];
                RowT r3 = xin[(size_t)e3.x * K + c];
                RowT r4 = xin[(size_t)e4.x * K + c];
                RowT r5 = xin[(size_t)e5.x * K + c];
                RowT r6 = xin[(size_t)e6.x * K + c];
                RowT r7 = xin[(size_t)e7.x * K + c];
                acc += term(e0, r0) + term(e1, r1) + term(e2, r2) + term(e3, r3)
                     + term(e4, r4) + term(e5, r5) + term(e6, r6) + term(e7, r7);
            }
            for (; j + 4 <= je; j += 4) {
                int4 e0 = edata[j], e1 = edata[j + 1], e2 = edata[j + 2], e3 = edata[j + 3];
                RowT r0 = xin[(size_t)e0.x * K + c];
                RowT r1 = xin[(size_t)e1.x * K + c];
                RowT r2 = xin[(size_t)e2.x * K + c];
                RowT r3 = xin[(size_t)e3.x * K + c];
                acc += term(e0, r0) + term(e1, r1) + term(e2, r2) + term(e3, r3);
            }
            for (; j < je; j++) {
                int4 e0 = edata[j];
                acc += term(e0, xin[(size_t)e0.x * K + c]);
            }
            sIn[i + half][c] = acc;
        }
    }
    __syncthreads();

    // ---- MLP layer A: sHid = relu(sIn @ wa + ba) ----
    float acc[NPB];
    #pragma unroll
    for (int i = 0; i < NPB; i++) acc[i] = ba[t];
    for (int k = 0; k < K; k++) {
        float w = wa[k * HID + t];
        #pragma unroll
        for (int i = 0; i < NPB; i++) acc[i] += sIn[i][k] * w;
    }
    #pragma unroll
    for (int i = 0; i < NPB; i++) sHid[i][t] = acc[i] > 0.f ? acc[i] : 0.f;
    __syncthreads();

    // ---- MLP layer B + outer relu ----
    float acc2[NPB];
    #pragma unroll
    for (int i = 0; i < NPB; i++) acc2[i] = bb[t];
    for (int k = 0; k < HID; k++) {
        float w = wb[k * HID + t];
        #pragma unroll
        for (int i = 0; i < NPB; i++) acc2[i] += sHid[i][k] * w;
    }
    #pragma unroll
    for (int i = 0; i < NPB; i++) {
        int node = node0 + i;
        float v = acc2[i] > 0.f ? acc2[i] : 0.f;
        if (POOL) {
            atomicAdd(&((float*)outv)[batch[node] * HID + t], v);
        } else {
            ((unsigned short*)outv)[(size_t)node * HID + t] = f2bf(v);
        }
    }
}

// ---------------------------------------------------------------------------
// Pool mean: batch is SORTED -> count[g] by binary search (wave-uniform).
// ---------------------------------------------------------------------------
__global__ void pool_div_kernel(const float* __restrict__ sums,
                                const int* __restrict__ batch,
                                float* __restrict__ out) {
    int i = blockIdx.x * blockDim.x + threadIdx.x;
    if (i >= N_GRAPHS * HID) return;
    int g = i / HID;
    int lo = 0, hi = N_NODES;
    while (lo < hi) { int mid = (lo + hi) >> 1; if (batch[mid] < g) lo = mid + 1; else hi = mid; }
    int start = lo;
    lo = 0; hi = N_NODES;
    while (lo < hi) { int mid = (lo + hi) >> 1; if (batch[mid] <= g) lo = mid + 1; else hi = mid; }
    float c = (float)(lo - start);
    out[i] = sums[i] / (c > 1.0f ? c : 1.0f);
}

extern "C" void kernel_launch(void* const* d_in, const int* in_sizes, int n_in,
                              void* d_out, int out_size, void* d_ws, size_t ws_size,
                              hipStream_t stream) {
    const float* x    = (const float*)d_in[0];
    const int*   ei   = (const int*)d_in[1];
    const float* ea   = (const float*)d_in[2];
    const int*   batch= (const int*)d_in[3];
    const float* el1w = (const float*)d_in[4];
    const float* el1b = (const float*)d_in[5];
    const float* w1a  = (const float*)d_in[6];
    const float* b1a  = (const float*)d_in[7];
    const float* w1b  = (const float*)d_in[8];
    const float* b1b  = (const float*)d_in[9];
    const float* el2w = (const float*)d_in[10];
    const float* el2b = (const float*)d_in[11];
    const float* w2a  = (const float*)d_in[12];
    const float* b2a  = (const float*)d_in[13];
    const float* w2b  = (const float*)d_in[14];
    const float* b2b  = (const float*)d_in[15];
    float* out = (float*)d_out;

    // workspace layout (16B-aligned sections)
    int4*  edata    = (int4*)d_ws;                      // [E] {src,a0,a1,a2}
    float* psum     = (float*)(edata + N_EDGES);        // [G*HID] 8192 f32
    int*   deg      = (int*)(psum + N_GRAPHS * HID);    // [N]
    int*   cursor   = deg + N_NODES;                    // [N]
    int*   rowptr   = cursor + N_NODES;                 // [N+1]
    int*   partials = rowptr + N_NODES + 1;             // [256]
    // ints so far: 8192+50000+50000+50001+256 = 158449; pad to 158452 (16B mult)
    unsigned short* hbf = (unsigned short*)((char*)psum + (size_t)158452 * 4);  // bf16 [N,HID]

    // ---- prep: CSR build (parallel scan) ----
    hipMemsetAsync(deg, 0, N_NODES * sizeof(int), stream);
    hist_kernel<<<(N_EDGES + 255) / 256, 256, 0, stream>>>(ei, deg);
    scan1_kernel<<<SCAN_BLOCKS, 256, 0, stream>>>(deg, partials);
    scan2_kernel<<<1, 256, 0, stream>>>(partials);
    scan3_kernel<<<SCAN_BLOCKS, 256, 0, stream>>>(deg, partials, rowptr, cursor);
    scatter_kernel<<<(N_EDGES + 255) / 256, 256, 0, stream>>>(ei, ea, cursor, edata);

    // ---- layer 1: f32 gather + scalar f32 MLP, h out as bf16 ----
    fused_layer<IN_CH, 8, false, false><<<N_NODES / 8, 128, 0, stream>>>(
        x, edata, rowptr, el1w, el1b, w1a, b1a, w1b, b1b, hbf, nullptr);

    // ---- layer 2: bf16 gather + scalar f32 MLP + pool atomics ----
    hipMemsetAsync(psum, 0, N_GRAPHS * HID * sizeof(float), stream);
    fused_layer<HID, 8, true, true><<<N_NODES / 8, 128, 0, stream>>>(
        hbf, edata, rowptr, el2w, el2b, w2a, b2a, w2b, b2b, psum, batch);

    // ---- mean (count via binary search on sorted batch) ----
    pool_div_kernel<<<(N_GRAPHS * HID + 255) / 256, 256, 0, stream>>>(psum, batch, out);
}